// Round 20
// baseline (81.629 us; speedup 1.0000x reference)
//
#include <hip/hip_runtime.h>
#include <math.h>

typedef _Float16 half8 __attribute__((ext_vector_type(8)));
typedef _Float16 half4 __attribute__((ext_vector_type(4)));
typedef float    f32x4 __attribute__((ext_vector_type(4)));

#define TOKENS  32768
#define HIDDEN  2048
#define EXPERTS 64
#define TOPK    8
#define BKW     64               // k per staged window
#define NWIN    (HIDDEN / BKW)   // 32
#define LDH     72               // LDS row stride in halves (144 B: 16B-aligned)

// ---------------------------------------------------------------------------
// r19 = r15 (best, 61.2us) with the wave->token split changed 4x16 -> 2x32:
// block = 128 thr (2 waves) owns the same 64 tokens x 64 experts x full K.
// Each wave computes 32 tokens (2 slabs), so B-fragments are read ONCE per
// k-slice and reused for both slabs: per-block-window LDS reads drop
// 80 -> 48 b128 (B-duplication 4x -> 2x), writes unchanged. Everything else
// identical to r15: fused kernel, fp16x3 split (hi*hi+hi*lo+lo*hi, fp32 acc),
// inline fp32->hi/lo staging, single-buffered LDS, 2 barriers/window,
// verified frag layouts (r8/r10). Grid 512 -> 2 blocks/CU as before.
// ---------------------------------------------------------------------------
__global__ __launch_bounds__(128, 1)
void router_w2(const float* __restrict__ A,
               const float* __restrict__ W,
               const float* __restrict__ bias,
               float* __restrict__ out) {
    __shared__ __align__(16) _Float16 hsm[4 * 64 * LDH];   // Ahi|Alo|Whi|Wlo = 36864 B
    _Float16* Ahs = hsm;
    _Float16* Als = hsm + 64 * LDH;
    _Float16* Whs = hsm + 2 * 64 * LDH;
    _Float16* Wls = hsm + 3 * 64 * LDH;

    const int tid = threadIdx.x;       // 0..127
    const int w   = tid >> 6;          // wave = 32-token half (2 slabs of 16)
    const int l   = tid & 63;
    const int g   = blockIdx.x;

    // A staging map: 8 row-rounds x (8 rows x 16 float4-chunks) -- coalesced
    const int s_tok = tid >> 4;        // 0..7
    const int s_c   = tid & 15;        // k-chunk: floats s_c*4..s_c*4+3
    // W staging map: 2 threads per expert row; each covers 32 floats
    const int we = tid >> 1;           // 0..63
    const int wc = tid & 1;            // half of the 64-float row

    const float* Abase = A + (size_t)g * 64 * HIDDEN;
    const float* WBase = W + (size_t)we * HIDDEN;

    f32x4 acc[2][4];                   // [token slab][expert tile]
    #pragma unroll
    for (int s = 0; s < 2; ++s)
        #pragma unroll
        for (int n = 0; n < 4; ++n) acc[s][n] = (f32x4){0.f, 0.f, 0.f, 0.f};

    float4 ar0, ar1, ar2, ar3, ar4, ar5, ar6, ar7;   // A: rows s_tok + 8r
    float4 wr0, wr1, wr2, wr3, wr4, wr5, wr6, wr7;   // W: 8 chunks of half-row

    #define LOADA(win) do {                                                  \
        const float* p_ = Abase + (size_t)(win) * BKW + s_c * 4;             \
        ar0 = *(const float4*)(p_ + (size_t)(s_tok     ) * HIDDEN);          \
        ar1 = *(const float4*)(p_ + (size_t)(s_tok +  8) * HIDDEN);          \
        ar2 = *(const float4*)(p_ + (size_t)(s_tok + 16) * HIDDEN);          \
        ar3 = *(const float4*)(p_ + (size_t)(s_tok + 24) * HIDDEN);          \
        ar4 = *(const float4*)(p_ + (size_t)(s_tok + 32) * HIDDEN);          \
        ar5 = *(const float4*)(p_ + (size_t)(s_tok + 40) * HIDDEN);          \
        ar6 = *(const float4*)(p_ + (size_t)(s_tok + 48) * HIDDEN);          \
        ar7 = *(const float4*)(p_ + (size_t)(s_tok + 56) * HIDDEN);          \
    } while (0)

    #define LOADW(win) do {                                                  \
        const float* q_ = WBase + (size_t)(win) * BKW + wc * 32;             \
        wr0 = *(const float4*)(q_);       wr1 = *(const float4*)(q_ + 4);    \
        wr2 = *(const float4*)(q_ + 8);   wr3 = *(const float4*)(q_ + 12);   \
        wr4 = *(const float4*)(q_ + 16);  wr5 = *(const float4*)(q_ + 20);   \
        wr6 = *(const float4*)(q_ + 24);  wr7 = *(const float4*)(q_ + 28);   \
    } while (0)

    // split one float4 into hi/lo half4 and store at half-offset OFF
    #define SPLIT4(HS, LS, v, OFF) do {                                      \
        _Float16 h0_ = (_Float16)(v).x, h1_ = (_Float16)(v).y;               \
        _Float16 h2_ = (_Float16)(v).z, h3_ = (_Float16)(v).w;               \
        half4 hh_ = {h0_, h1_, h2_, h3_};                                    \
        half4 ll_ = {(_Float16)((v).x - (float)h0_),                         \
                     (_Float16)((v).y - (float)h1_),                         \
                     (_Float16)((v).z - (float)h2_),                         \
                     (_Float16)((v).w - (float)h3_)};                        \
        *(half4*)(&(HS)[(OFF)]) = hh_;                                       \
        *(half4*)(&(LS)[(OFF)]) = ll_;                                       \
    } while (0)

    #define STAGE() do {                                                     \
        SPLIT4(Ahs, Als, ar0, (s_tok     ) * LDH + s_c * 4);                 \
        SPLIT4(Ahs, Als, ar1, (s_tok +  8) * LDH + s_c * 4);                 \
        SPLIT4(Ahs, Als, ar2, (s_tok + 16) * LDH + s_c * 4);                 \
        SPLIT4(Ahs, Als, ar3, (s_tok + 24) * LDH + s_c * 4);                 \
        SPLIT4(Ahs, Als, ar4, (s_tok + 32) * LDH + s_c * 4);                 \
        SPLIT4(Ahs, Als, ar5, (s_tok + 40) * LDH + s_c * 4);                 \
        SPLIT4(Ahs, Als, ar6, (s_tok + 48) * LDH + s_c * 4);                 \
        SPLIT4(Ahs, Als, ar7, (s_tok + 56) * LDH + s_c * 4);                 \
        SPLIT4(Whs, Wls, wr0, we * LDH + wc * 32);                           \
        SPLIT4(Whs, Wls, wr1, we * LDH + wc * 32 + 4);                       \
        SPLIT4(Whs, Wls, wr2, we * LDH + wc * 32 + 8);                       \
        SPLIT4(Whs, Wls, wr3, we * LDH + wc * 32 + 12);                      \
        SPLIT4(Whs, Wls, wr4, we * LDH + wc * 32 + 16);                      \
        SPLIT4(Whs, Wls, wr5, we * LDH + wc * 32 + 20);                      \
        SPLIT4(Whs, Wls, wr6, we * LDH + wc * 32 + 24);                      \
        SPLIT4(Whs, Wls, wr7, we * LDH + wc * 32 + 28);                      \
    } while (0)

    LOADA(0);
    LOADW(0);

    #pragma unroll 1
    for (int win = 0; win < NWIN; ++win) {
        __syncthreads();                       // previous window fully consumed
        STAGE();
        __syncthreads();                       // window published

        if (win + 1 < NWIN) {                  // next-window loads fly during MFMA
            LOADA(win + 1);
            LOADW(win + 1);
        }

        #pragma unroll
        for (int ks = 0; ks < 2; ++ks) {
            const int ko = ks * 32 + (l >> 4) * 8;
            // A frags for both slabs of this wave's 32 tokens
            half8 ahi0 = *(const half8*)(&Ahs[(w * 32 +      (l & 15)) * LDH + ko]);
            half8 alo0 = *(const half8*)(&Als[(w * 32 +      (l & 15)) * LDH + ko]);
            half8 ahi1 = *(const half8*)(&Ahs[(w * 32 + 16 + (l & 15)) * LDH + ko]);
            half8 alo1 = *(const half8*)(&Als[(w * 32 + 16 + (l & 15)) * LDH + ko]);
            #pragma unroll
            for (int n = 0; n < 4; ++n) {      // B frags read ONCE, used twice
                half8 bh = *(const half8*)(&Whs[(n * 16 + (l & 15)) * LDH + ko]);
                half8 bl = *(const half8*)(&Wls[(n * 16 + (l & 15)) * LDH + ko]);
                acc[0][n] = __builtin_amdgcn_mfma_f32_16x16x32_f16(ahi0, bh, acc[0][n], 0, 0, 0);
                acc[0][n] = __builtin_amdgcn_mfma_f32_16x16x32_f16(ahi0, bl, acc[0][n], 0, 0, 0);
                acc[0][n] = __builtin_amdgcn_mfma_f32_16x16x32_f16(alo0, bh, acc[0][n], 0, 0, 0);
                acc[1][n] = __builtin_amdgcn_mfma_f32_16x16x32_f16(ahi1, bh, acc[1][n], 0, 0, 0);
                acc[1][n] = __builtin_amdgcn_mfma_f32_16x16x32_f16(ahi1, bl, acc[1][n], 0, 0, 0);
                acc[1][n] = __builtin_amdgcn_mfma_f32_16x16x32_f16(alo1, bh, acc[1][n], 0, 0, 0);
            }
        }
    }
    #undef LOADA
    #undef LOADW
    #undef SPLIT4
    #undef STAGE

    // ---- epilogue: logits (+bias) to LDS, top-8 + softmax + scatter ----
    __syncthreads();                           // staging LDS dead; alias as float
    float* lg = (float*)hsm;                   // [64 tok][68]
    float* sc = (float*)hsm + 64 * 68;         // [64 tok][65]

    // D layout (verified r8): token row = (l>>4)*4+q, expert col = n*16+(l&15)
    #pragma unroll
    for (int s = 0; s < 2; ++s)
        #pragma unroll
        for (int n = 0; n < 4; ++n) {
            float b = bias[n * 16 + (l & 15)];
            #pragma unroll
            for (int q = 0; q < 4; ++q) {
                int trow = w * 32 + s * 16 + (l >> 4) * 4 + q;
                lg[trow * 68 + n * 16 + (l & 15)] = acc[s][n][q] + b;
            }
        }
    for (int i = tid; i < 64 * 65; i += 128) sc[i] = 0.f;
    __syncthreads();

    if (tid < 64) {
        const int t = tid;
        float v[64];
        #pragma unroll
        for (int e = 0; e < 64; ++e) v[e] = lg[t * 68 + e];

        float tvals[TOPK]; int tix[TOPK]; float probs[TOPK];
        unsigned long long chosen = 0ull;
        #pragma unroll
        for (int j = 0; j < TOPK; ++j) {
            float best = -INFINITY; int bi = 0;
            #pragma unroll
            for (int e = 0; e < 64; ++e) {
                bool ok = ((chosen >> e) & 1ull) == 0ull;
                if (ok && v[e] > best) { best = v[e]; bi = e; }  // strict >: lowest idx on tie
            }
            chosen |= (1ull << bi);
            tvals[j] = best; tix[j] = bi;
        }
        float m = tvals[0];
        float ssum = 0.f;
        #pragma unroll
        for (int j = 0; j < TOPK; ++j) { probs[j] = __expf(tvals[j] - m); ssum += probs[j]; }
        float inv = 1.f / ssum;
        #pragma unroll
        for (int j = 0; j < TOPK; ++j) probs[j] *= inv;

        #pragma unroll
        for (int j = 0; j < TOPK; ++j) sc[t * 65 + tix[j]] = probs[j];

        float* oidx = out + (size_t)TOKENS * EXPERTS;
        const int token = g * 64 + t;
        #pragma unroll
        for (int j = 0; j < TOPK; ++j) oidx[(size_t)token * TOPK + j] = (float)tix[j];
    }
    __syncthreads();

    // ---- coalesced score write: 64 tokens x 64 experts = 1024 float4 ----
    float* oscore = out + (size_t)g * 4096;
    #pragma unroll
    for (int p = 0; p < 8; ++p) {
        int fi  = tid + 128 * p;               // float4 index 0..1023
        int tok = fi >> 4;
        int es  = (fi & 15) * 4;
        float4 vv;
        vv.x = sc[tok * 65 + es + 0];
        vv.y = sc[tok * 65 + es + 1];
        vv.z = sc[tok * 65 + es + 2];
        vv.w = sc[tok * 65 + es + 3];
        *(float4*)(oscore + (size_t)fi * 4) = vv;
    }
}

extern "C" void kernel_launch(void* const* d_in, const int* in_sizes, int n_in,
                              void* d_out, int out_size, void* d_ws, size_t ws_size,
                              hipStream_t stream) {
    const float* A    = (const float*)d_in[0];   // [32768, 2048] fp32
    const float* W    = (const float*)d_in[1];   // [64, 2048] fp32
    const float* bias = (const float*)d_in[2];   // [64] fp32
    float* out = (float*)d_out;                  // scores (32768*64) ++ idx (32768*8)
    (void)d_ws; (void)ws_size;

    router_w2<<<TOKENS / 64, 128, 0, stream>>>(A, W, bias, out);
}

// Round 21
// 62.152 us; speedup vs baseline: 1.3134x; 1.3134x over previous
//
#include <hip/hip_runtime.h>
#include <math.h>

typedef _Float16 half8 __attribute__((ext_vector_type(8)));
typedef _Float16 half4 __attribute__((ext_vector_type(4)));
typedef float    f32x4 __attribute__((ext_vector_type(4)));

#define TOKENS  32768
#define HIDDEN  2048
#define EXPERTS 64
#define TOPK    8
#define BKW     64               // k per staged window
#define NWIN    (HIDDEN / BKW)   // 32
#define LDH     72               // LDS row stride in halves (144 B: 16B-aligned)

// ---------------------------------------------------------------------------
// r20 = r15 (best, 61.2us) with ONLY the wave->output mapping changed:
// wave (tg2,eg2) = (w>>1, w&1) computes 32 tokens x 32 experts (2 slabs x
// 2 expert tiles; acc still 4 x f32x4 = 16 VGPR). B-frags are read once per
// wave instead of by all 4 waves: block LDS reads/window drop 80 -> 64 b128
// (B 64 -> 32, A 16 -> 32). Same 256 thr / 4 waves / 64 tokens / grid 512 /
// staging maps / single-buffered LDS / 2 __syncthreads per window as r15.
// fp16x3 split numerics (hi*hi + hi*lo + lo*hi, fp32 acc), frag layouts
// verified (r8/r10).
// ---------------------------------------------------------------------------
__global__ __launch_bounds__(256, 1)
void router_22(const float* __restrict__ A,
               const float* __restrict__ W,
               const float* __restrict__ bias,
               float* __restrict__ out) {
    __shared__ __align__(16) _Float16 hsm[4 * 64 * LDH];   // Ahi|Alo|Whi|Wlo = 36864 B
    _Float16* Ahs = hsm;
    _Float16* Als = hsm + 64 * LDH;
    _Float16* Whs = hsm + 2 * 64 * LDH;
    _Float16* Wls = hsm + 3 * 64 * LDH;

    const int tid = threadIdx.x;
    const int w   = tid >> 6;
    const int l   = tid & 63;
    const int g   = blockIdx.x;
    const int tg2 = w >> 1;            // token half: tokens tg2*32 .. +32
    const int eg2 = w & 1;             // expert half: experts eg2*32 .. +32

    // A staging map: 4 rounds x (16 rows x 16 float4-chunks) -- coalesced
    const int s_tok = tid >> 4;        // 0..15
    const int s_c   = tid & 15;        // k-chunk: floats s_c*4..s_c*4+3
    // W staging map: thread -> expert row, two 8-float chunks (wc*8, wc*8+32)
    const int we = tid >> 2;           // 0..63
    const int wc = tid & 3;

    const float* Abase = A + (size_t)g * 64 * HIDDEN;
    const float* WBase = W + (size_t)we * HIDDEN;

    f32x4 acc[2][2];                   // [token slab][expert tile]
    #pragma unroll
    for (int s = 0; s < 2; ++s)
        #pragma unroll
        for (int n = 0; n < 2; ++n) acc[s][n] = (f32x4){0.f, 0.f, 0.f, 0.f};

    float4 ar0, ar1, ar2, ar3;         // A staging regs (4 rows)
    float4 wr0, wr1, wr2, wr3;         // W staging regs (2 chunks x 2 float4)

    #define LOADA(win) do {                                                  \
        const float* p_ = Abase + (size_t)(win) * BKW + s_c * 4;             \
        ar0 = *(const float4*)(p_ + (size_t)(s_tok     ) * HIDDEN);          \
        ar1 = *(const float4*)(p_ + (size_t)(s_tok + 16) * HIDDEN);          \
        ar2 = *(const float4*)(p_ + (size_t)(s_tok + 32) * HIDDEN);          \
        ar3 = *(const float4*)(p_ + (size_t)(s_tok + 48) * HIDDEN);          \
    } while (0)

    #define LOADW(win) do {                                                  \
        const float* q_ = WBase + (size_t)(win) * BKW + wc * 8;              \
        wr0 = *(const float4*)(q_);                                          \
        wr1 = *(const float4*)(q_ + 4);                                      \
        wr2 = *(const float4*)(q_ + 32);                                     \
        wr3 = *(const float4*)(q_ + 36);                                     \
    } while (0)

    // split one float4 into hi/lo half4 and store to (HS,LS) at half-offset OFF
    #define SPLIT4(HS, LS, v, OFF) do {                                      \
        _Float16 h0_ = (_Float16)(v).x, h1_ = (_Float16)(v).y;               \
        _Float16 h2_ = (_Float16)(v).z, h3_ = (_Float16)(v).w;               \
        half4 hh_ = {h0_, h1_, h2_, h3_};                                    \
        half4 ll_ = {(_Float16)((v).x - (float)h0_),                         \
                     (_Float16)((v).y - (float)h1_),                         \
                     (_Float16)((v).z - (float)h2_),                         \
                     (_Float16)((v).w - (float)h3_)};                        \
        *(half4*)(&(HS)[(OFF)]) = hh_;                                       \
        *(half4*)(&(LS)[(OFF)]) = ll_;                                       \
    } while (0)

    #define STAGE() do {                                                     \
        SPLIT4(Ahs, Als, ar0, (s_tok     ) * LDH + s_c * 4);                 \
        SPLIT4(Ahs, Als, ar1, (s_tok + 16) * LDH + s_c * 4);                 \
        SPLIT4(Ahs, Als, ar2, (s_tok + 32) * LDH + s_c * 4);                 \
        SPLIT4(Ahs, Als, ar3, (s_tok + 48) * LDH + s_c * 4);                 \
        SPLIT4(Whs, Wls, wr0, we * LDH + wc * 8);                            \
        SPLIT4(Whs, Wls, wr1, we * LDH + wc * 8 + 4);                        \
        SPLIT4(Whs, Wls, wr2, we * LDH + wc * 8 + 32);                       \
        SPLIT4(Whs, Wls, wr3, we * LDH + wc * 8 + 36);                       \
    } while (0)

    LOADA(0);
    LOADW(0);

    #pragma unroll 1
    for (int win = 0; win < NWIN; ++win) {
        __syncthreads();                       // previous window fully consumed
        STAGE();
        __syncthreads();                       // window published

        if (win + 1 < NWIN) {                  // next-window loads fly during MFMA
            LOADA(win + 1);
            LOADW(win + 1);
        }

        #pragma unroll
        for (int ks = 0; ks < 2; ++ks) {
            const int ko = ks * 32 + (l >> 4) * 8;
            // A frags: both slabs of this wave's 32 tokens
            half8 ahi0 = *(const half8*)(&Ahs[(tg2 * 32 +      (l & 15)) * LDH + ko]);
            half8 alo0 = *(const half8*)(&Als[(tg2 * 32 +      (l & 15)) * LDH + ko]);
            half8 ahi1 = *(const half8*)(&Ahs[(tg2 * 32 + 16 + (l & 15)) * LDH + ko]);
            half8 alo1 = *(const half8*)(&Als[(tg2 * 32 + 16 + (l & 15)) * LDH + ko]);
            #pragma unroll
            for (int n = 0; n < 2; ++n) {      // B frags read once, used for 2 slabs
                const int er = eg2 * 32 + n * 16 + (l & 15);
                half8 bh = *(const half8*)(&Whs[er * LDH + ko]);
                half8 bl = *(const half8*)(&Wls[er * LDH + ko]);
                acc[0][n] = __builtin_amdgcn_mfma_f32_16x16x32_f16(ahi0, bh, acc[0][n], 0, 0, 0);
                acc[0][n] = __builtin_amdgcn_mfma_f32_16x16x32_f16(ahi0, bl, acc[0][n], 0, 0, 0);
                acc[0][n] = __builtin_amdgcn_mfma_f32_16x16x32_f16(alo0, bh, acc[0][n], 0, 0, 0);
                acc[1][n] = __builtin_amdgcn_mfma_f32_16x16x32_f16(ahi1, bh, acc[1][n], 0, 0, 0);
                acc[1][n] = __builtin_amdgcn_mfma_f32_16x16x32_f16(ahi1, bl, acc[1][n], 0, 0, 0);
                acc[1][n] = __builtin_amdgcn_mfma_f32_16x16x32_f16(alo1, bh, acc[1][n], 0, 0, 0);
            }
        }
    }
    #undef LOADA
    #undef LOADW
    #undef SPLIT4
    #undef STAGE

    // ---- epilogue: logits (+bias) to LDS, top-8 + softmax + scatter ----
    __syncthreads();                           // staging LDS dead; alias as float
    float* lg = (float*)hsm;                   // [64 tok][68]
    float* sc = (float*)hsm + 64 * 68;         // [64 tok][65]

    // D layout (verified r8): token row = (l>>4)*4+q within slab,
    // expert col = (l&15) within tile
    #pragma unroll
    for (int s = 0; s < 2; ++s)
        #pragma unroll
        for (int n = 0; n < 2; ++n) {
            const int ecol = eg2 * 32 + n * 16 + (l & 15);
            float b = bias[ecol];
            #pragma unroll
            for (int q = 0; q < 4; ++q) {
                int trow = tg2 * 32 + s * 16 + (l >> 4) * 4 + q;
                lg[trow * 68 + ecol] = acc[s][n][q] + b;
            }
        }
    for (int i = tid; i < 64 * 65; i += 256) sc[i] = 0.f;
    __syncthreads();

    if (tid < 64) {
        const int t = tid;
        float v[64];
        #pragma unroll
        for (int e = 0; e < 64; ++e) v[e] = lg[t * 68 + e];

        float tvals[TOPK]; int tix[TOPK]; float probs[TOPK];
        unsigned long long chosen = 0ull;
        #pragma unroll
        for (int j = 0; j < TOPK; ++j) {
            float best = -INFINITY; int bi = 0;
            #pragma unroll
            for (int e = 0; e < 64; ++e) {
                bool ok = ((chosen >> e) & 1ull) == 0ull;
                if (ok && v[e] > best) { best = v[e]; bi = e; }  // strict >: lowest idx on tie
            }
            chosen |= (1ull << bi);
            tvals[j] = best; tix[j] = bi;
        }
        float m = tvals[0];
        float ssum = 0.f;
        #pragma unroll
        for (int j = 0; j < TOPK; ++j) { probs[j] = __expf(tvals[j] - m); ssum += probs[j]; }
        float inv = 1.f / ssum;
        #pragma unroll
        for (int j = 0; j < TOPK; ++j) probs[j] *= inv;

        #pragma unroll
        for (int j = 0; j < TOPK; ++j) sc[t * 65 + tix[j]] = probs[j];

        float* oidx = out + (size_t)TOKENS * EXPERTS;
        const int token = g * 64 + t;
        #pragma unroll
        for (int j = 0; j < TOPK; ++j) oidx[(size_t)token * TOPK + j] = (float)tix[j];
    }
    __syncthreads();

    // ---- coalesced score write: 64 tokens x 64 experts = 1024 float4 ----
    float* oscore = out + (size_t)g * 4096;
    #pragma unroll
    for (int p = 0; p < 4; ++p) {
        int fi  = tid + 256 * p;               // float4 index 0..1023
        int tok = fi >> 4;
        int es  = (fi & 15) * 4;
        float4 vv;
        vv.x = sc[tok * 65 + es + 0];
        vv.y = sc[tok * 65 + es + 1];
        vv.z = sc[tok * 65 + es + 2];
        vv.w = sc[tok * 65 + es + 3];
        *(float4*)(oscore + (size_t)fi * 4) = vv;
    }
}

extern "C" void kernel_launch(void* const* d_in, const int* in_sizes, int n_in,
                              void* d_out, int out_size, void* d_ws, size_t ws_size,
                              hipStream_t stream) {
    const float* A    = (const float*)d_in[0];   // [32768, 2048] fp32
    const float* W    = (const float*)d_in[1];   // [64, 2048] fp32
    const float* bias = (const float*)d_in[2];   // [64] fp32
    float* out = (float*)d_out;                  // scores (32768*64) ++ idx (32768*8)
    (void)d_ws; (void)ws_size;

    router_22<<<TOKENS / 64, 256, 0, stream>>>(A, W, bias, out);
}